// Round 1
// baseline (265.733 us; speedup 1.0000x reference)
//
#include <hip/hip_runtime.h>
#include <hip/hip_bf16.h>

#define NHEAD 12
#define HD 64
#define SEQ 2048
#define NB 4
#define HDIM 768
#define MTOT (NB * SEQ)   // 8192

typedef float f32x4 __attribute__((ext_vector_type(4)));
typedef unsigned int u32x4 __attribute__((ext_vector_type(4)));

__device__ inline unsigned short f2bf(float f) {
    union { float f; unsigned u; } v; v.f = f;
    unsigned r = v.u + 0x7fffu + ((v.u >> 16) & 1u);
    return (unsigned short)(r >> 16);
}
__device__ inline float bf2f(unsigned short u) {
    union { unsigned u; float f; } v; v.u = ((unsigned)u) << 16;
    return v.f;
}

__device__ inline void mfma_bf16(f32x4& c, const u32x4& a, const u32x4& b) {
    asm("v_mfma_f32_16x16x32_bf16 %0, %1, %2, %0" : "+v"(c) : "v"(a), "v"(b));
}

// ---------------------------------------------------------------------------
// QKV projection: Y = X @ W + bias.  X fp32 [8192][768], W fp32 [768][768].
// z=0 -> Q fp32 (scaled by 1/8), z=1 -> K bf16, z=2 -> V bf16; all head-major
// [b][h][s][d].
// ---------------------------------------------------------------------------
__global__ __launch_bounds__(256) void qkv_gemm(
    const float* __restrict__ X,
    const float* __restrict__ W0, const float* __restrict__ b0,
    const float* __restrict__ W1, const float* __restrict__ b1,
    const float* __restrict__ W2, const float* __restrict__ b2,
    float* __restrict__ Qf, unsigned short* __restrict__ Kb,
    unsigned short* __restrict__ Vb)
{
    const int z = blockIdx.z;
    const float* W    = (z == 0) ? W0 : (z == 1) ? W1 : W2;
    const float* bias = (z == 0) ? b0 : (z == 1) ? b1 : b2;

    __shared__ __align__(16) unsigned short As[128][36];  // [m][k], pad 36
    __shared__ __align__(16) unsigned short Bs[128][36];  // [n][k] (transposed)

    const int t = threadIdx.x;
    const int lane = t & 63;
    const int wid = t >> 6;
    const int wm = wid >> 1, wn = wid & 1;
    const int g = lane >> 4, r16 = lane & 15;

    const int m0 = blockIdx.x * 128;
    const int n0 = blockIdx.y * 128;

    f32x4 acc[4][4] = {};

    for (int k0 = 0; k0 < HDIM; k0 += 32) {
        __syncthreads();
        // stage A: 128x32 fp32 -> bf16, row-major [m][k]
        #pragma unroll
        for (int i = 0; i < 4; i++) {
            int f = i * 256 + t;              // 0..1023
            int row = f >> 3, c4 = f & 7;
            float4 v = *(const float4*)(X + (size_t)(m0 + row) * HDIM + k0 + c4 * 4);
            ushort4 w4;
            w4.x = f2bf(v.x); w4.y = f2bf(v.y); w4.z = f2bf(v.z); w4.w = f2bf(v.w);
            *(ushort4*)&As[row][c4 * 4] = w4;
        }
        // stage B transposed: W[k][n] -> Bs[n][k]; each thread handles a
        // (4 k-rows) x (4 n-cols) micro-tile so LDS writes are 8B.
        {
            int kk4 = (t >> 5) * 4;           // 0,4,...,28
            int c4  = t & 31;                 // n/4
            const float* wp = W + (size_t)(k0 + kk4) * HDIM + n0 + c4 * 4;
            float4 v0 = *(const float4*)(wp + 0 * HDIM);
            float4 v1 = *(const float4*)(wp + 1 * HDIM);
            float4 v2 = *(const float4*)(wp + 2 * HDIM);
            float4 v3 = *(const float4*)(wp + 3 * HDIM);
            const float e0[4] = {v0.x, v0.y, v0.z, v0.w};
            const float e1[4] = {v1.x, v1.y, v1.z, v1.w};
            const float e2[4] = {v2.x, v2.y, v2.z, v2.w};
            const float e3[4] = {v3.x, v3.y, v3.z, v3.w};
            #pragma unroll
            for (int e = 0; e < 4; e++) {
                ushort4 w4;
                w4.x = f2bf(e0[e]); w4.y = f2bf(e1[e]);
                w4.z = f2bf(e2[e]); w4.w = f2bf(e3[e]);
                *(ushort4*)&Bs[c4 * 4 + e][kk4] = w4;
            }
        }
        __syncthreads();

        u32x4 af[4], bf[4];
        #pragma unroll
        for (int fm = 0; fm < 4; fm++) {
            const unsigned short* p = &As[wm * 64 + fm * 16 + r16][0];
            uint2 lo = *(const uint2*)(p + 4 * g);
            uint2 hi = *(const uint2*)(p + 16 + 4 * g);
            u32x4 a; a.x = lo.x; a.y = lo.y; a.z = hi.x; a.w = hi.y;
            af[fm] = a;
        }
        #pragma unroll
        for (int fn = 0; fn < 4; fn++) {
            const unsigned short* p = &Bs[wn * 64 + fn * 16 + r16][0];
            uint2 lo = *(const uint2*)(p + 4 * g);
            uint2 hi = *(const uint2*)(p + 16 + 4 * g);
            u32x4 b; b.x = lo.x; b.y = lo.y; b.z = hi.x; b.w = hi.y;
            bf[fn] = b;
        }
        #pragma unroll
        for (int fm = 0; fm < 4; fm++)
            #pragma unroll
            for (int fn = 0; fn < 4; fn++)
                mfma_bf16(acc[fm][fn], af[fm], bf[fn]);
    }

    const float scale = (z == 0) ? 0.125f : 1.0f;  // fold 1/sqrt(64) into Q
    #pragma unroll
    for (int fm = 0; fm < 4; fm++) {
        #pragma unroll
        for (int fn = 0; fn < 4; fn++) {
            const int col = n0 + wn * 64 + fn * 16 + r16;
            const float bc = bias[col];
            const int h = col >> 6, d = col & 63;
            #pragma unroll
            for (int r = 0; r < 4; r++) {
                const int m = m0 + wm * 64 + fm * 16 + 4 * g + r;
                const int b = m >> 11, s = m & (SEQ - 1);
                const float val = (acc[fm][fn][r] + bc) * scale;
                const size_t idx = (((size_t)b * NHEAD + h) * SEQ + s) * HD + d;
                if (z == 0)      Qf[idx] = val;
                else if (z == 1) Kb[idx] = f2bf(val);
                else             Vb[idx] = f2bf(val);
            }
        }
    }
}

// ---------------------------------------------------------------------------
// Banded attention. One block = one (b*h, 64-query tile). 128 threads:
// 2 threads per query. Window |i-j| <= 32 -> 65 keys/query.
// ---------------------------------------------------------------------------
__global__ __launch_bounds__(128) void attn_kernel(
    const float* __restrict__ Qf, const unsigned short* __restrict__ Kb,
    const unsigned short* __restrict__ Vb, unsigned short* __restrict__ Cb)
{
    __shared__ __align__(16) unsigned short Ks[128][68];
    __shared__ __align__(16) unsigned short Vs[128][68];
    __shared__ float Sc[64][67];

    const int t = threadIdx.x;
    const int q0 = blockIdx.x * 64;
    const int bh = blockIdx.y;
    const int b = bh / NHEAD, h = bh % NHEAD;
    const size_t base = (size_t)bh * SEQ * HD;
    const int kstart = q0 - 32;

    // stage K/V rows [q0-32, q0+96)
    #pragma unroll
    for (int i = 0; i < 16; i++) {
        int f = i * 128 + t;              // 0..2047
        int row = f >> 4, c4 = f & 15;
        int j = kstart + row;
        ushort4 kv = make_ushort4(0, 0, 0, 0);
        ushort4 vv = make_ushort4(0, 0, 0, 0);
        if (j >= 0 && j < SEQ) {
            kv = *(const ushort4*)(Kb + base + (size_t)j * HD + c4 * 4);
            vv = *(const ushort4*)(Vb + base + (size_t)j * HD + c4 * 4);
        }
        *(ushort4*)&Ks[row][c4 * 4] = kv;
        *(ushort4*)&Vs[row][c4 * 4] = vv;
    }

    const int q = t >> 1;
    const int half = t & 1;
    const int i_glob = q0 + q;

    float qr[64];
    #pragma unroll
    for (int d4 = 0; d4 < 16; d4++) {
        float4 v = *(const float4*)(Qf + base + (size_t)i_glob * HD + d4 * 4);
        qr[d4 * 4 + 0] = v.x; qr[d4 * 4 + 1] = v.y;
        qr[d4 * 4 + 2] = v.z; qr[d4 * 4 + 3] = v.w;
    }
    __syncthreads();

    // scores: half 0 -> jj 0..32, half 1 -> jj 33..64
    const int jj0 = half ? 33 : 0;
    const int jjn = half ? 32 : 33;
    for (int u = 0; u < jjn; u++) {
        int jj = jj0 + u;
        int jg = i_glob - 32 + jj;
        float s = -1e30f;
        if (jg >= 0 && jg < SEQ) {
            int row = q + jj;
            float a = 0.f;
            #pragma unroll
            for (int d4 = 0; d4 < 16; d4++) {
                ushort4 kv = *(const ushort4*)&Ks[row][d4 * 4];
                a += qr[d4 * 4 + 0] * bf2f(kv.x) + qr[d4 * 4 + 1] * bf2f(kv.y)
                   + qr[d4 * 4 + 2] * bf2f(kv.z) + qr[d4 * 4 + 3] * bf2f(kv.w);
            }
            s = a;  // Q already carries 1/sqrt(HD)
        }
        Sc[q][jj] = s;
    }
    __syncthreads();

    // softmax, one thread per query
    if (t < 64) {
        float m = -1e30f;
        for (int jj = 0; jj < 65; jj++) m = fmaxf(m, Sc[t][jj]);
        float sum = 0.f;
        for (int jj = 0; jj < 65; jj++) {
            float e = __expf(Sc[t][jj] - m);
            Sc[t][jj] = e;
            sum += e;
        }
        float inv = 1.f / sum;
        for (int jj = 0; jj < 65; jj++) Sc[t][jj] *= inv;
    }
    __syncthreads();

    // PV: thread (q, half) computes dims [half*32, half*32+32)
    float ctx[32] = {};
    for (int jj = 0; jj < 65; jj++) {
        float p = Sc[q][jj];
        int row = q + jj;
        #pragma unroll
        for (int d4 = 0; d4 < 8; d4++) {
            ushort4 vv = *(const ushort4*)&Vs[row][half * 32 + d4 * 4];
            ctx[d4 * 4 + 0] += p * bf2f(vv.x);
            ctx[d4 * 4 + 1] += p * bf2f(vv.y);
            ctx[d4 * 4 + 2] += p * bf2f(vv.z);
            ctx[d4 * 4 + 3] += p * bf2f(vv.w);
        }
    }
    // ctx -> [b][s][h][d] bf16 (row-major [8192][768] for the Wo GEMM)
    unsigned short* dst = Cb + (((size_t)b * SEQ + i_glob) * NHEAD + h) * HD + half * 32;
    #pragma unroll
    for (int d4 = 0; d4 < 8; d4++) {
        ushort4 w;
        w.x = f2bf(ctx[d4 * 4 + 0]); w.y = f2bf(ctx[d4 * 4 + 1]);
        w.z = f2bf(ctx[d4 * 4 + 2]); w.w = f2bf(ctx[d4 * 4 + 3]);
        *(ushort4*)(dst + d4 * 4) = w;
    }
}

// ---------------------------------------------------------------------------
// Output projection: out = ctx @ Wo + bo.  ctx bf16 [8192][768], out fp32.
// ---------------------------------------------------------------------------
__global__ __launch_bounds__(256) void out_gemm(
    const unsigned short* __restrict__ Cb,
    const float* __restrict__ Wo, const float* __restrict__ bo,
    float* __restrict__ out)
{
    __shared__ __align__(16) unsigned short As[128][36];
    __shared__ __align__(16) unsigned short Bs[128][36];

    const int t = threadIdx.x;
    const int lane = t & 63;
    const int wid = t >> 6;
    const int wm = wid >> 1, wn = wid & 1;
    const int g = lane >> 4, r16 = lane & 15;

    const int m0 = blockIdx.x * 128;
    const int n0 = blockIdx.y * 128;

    f32x4 acc[4][4] = {};

    for (int k0 = 0; k0 < HDIM; k0 += 32) {
        __syncthreads();
        #pragma unroll
        for (int i = 0; i < 4; i++) {
            int f = i * 256 + t;
            int row = f >> 3, c4 = f & 7;
            ushort4 v = *(const ushort4*)(Cb + (size_t)(m0 + row) * HDIM + k0 + c4 * 4);
            *(ushort4*)&As[row][c4 * 4] = v;
        }
        {
            int kk4 = (t >> 5) * 4;
            int c4  = t & 31;
            const float* wp = Wo + (size_t)(k0 + kk4) * HDIM + n0 + c4 * 4;
            float4 v0 = *(const float4*)(wp + 0 * HDIM);
            float4 v1 = *(const float4*)(wp + 1 * HDIM);
            float4 v2 = *(const float4*)(wp + 2 * HDIM);
            float4 v3 = *(const float4*)(wp + 3 * HDIM);
            const float e0[4] = {v0.x, v0.y, v0.z, v0.w};
            const float e1[4] = {v1.x, v1.y, v1.z, v1.w};
            const float e2[4] = {v2.x, v2.y, v2.z, v2.w};
            const float e3[4] = {v3.x, v3.y, v3.z, v3.w};
            #pragma unroll
            for (int e = 0; e < 4; e++) {
                ushort4 w4;
                w4.x = f2bf(e0[e]); w4.y = f2bf(e1[e]);
                w4.z = f2bf(e2[e]); w4.w = f2bf(e3[e]);
                *(ushort4*)&Bs[c4 * 4 + e][kk4] = w4;
            }
        }
        __syncthreads();

        u32x4 af[4], bfv[4];
        #pragma unroll
        for (int fm = 0; fm < 4; fm++) {
            const unsigned short* p = &As[wm * 64 + fm * 16 + r16][0];
            uint2 lo = *(const uint2*)(p + 4 * g);
            uint2 hi = *(const uint2*)(p + 16 + 4 * g);
            u32x4 a; a.x = lo.x; a.y = lo.y; a.z = hi.x; a.w = hi.y;
            af[fm] = a;
        }
        #pragma unroll
        for (int fn = 0; fn < 4; fn++) {
            const unsigned short* p = &Bs[wn * 64 + fn * 16 + r16][0];
            uint2 lo = *(const uint2*)(p + 4 * g);
            uint2 hi = *(const uint2*)(p + 16 + 4 * g);
            u32x4 b; b.x = lo.x; b.y = lo.y; b.z = hi.x; b.w = hi.y;
            bfv[fn] = b;
        }
        #pragma unroll
        for (int fm = 0; fm < 4; fm++)
            #pragma unroll
            for (int fn = 0; fn < 4; fn++)
                mfma_bf16(acc[fm][fn], af[fm], bfv[fn]);
    }

    #pragma unroll
    for (int fm = 0; fm < 4; fm++) {
        #pragma unroll
        for (int fn = 0; fn < 4; fn++) {
            const int col = n0 + wn * 64 + fn * 16 + r16;
            const float bc = bo[col];
            #pragma unroll
            for (int r = 0; r < 4; r++) {
                const int m = m0 + wm * 64 + fm * 16 + 4 * g + r;
                out[(size_t)m * HDIM + col] = acc[fm][fn][r] + bc;
            }
        }
    }
}

// ---------------------------------------------------------------------------
extern "C" void kernel_launch(void* const* d_in, const int* in_sizes, int n_in,
                              void* d_out, int out_size, void* d_ws, size_t ws_size,
                              hipStream_t stream)
{
    const float* X  = (const float*)d_in[0];
    const float* Wq = (const float*)d_in[1];
    const float* bq = (const float*)d_in[2];
    const float* Wk = (const float*)d_in[3];
    const float* bk = (const float*)d_in[4];
    const float* Wv = (const float*)d_in[5];
    const float* bv = (const float*)d_in[6];
    const float* Wo = (const float*)d_in[7];
    const float* bo = (const float*)d_in[8];
    float* out = (float*)d_out;

    // Q (fp32, 25.2 MB) lives in d_out: consumed by attention, then d_out is
    // fully overwritten by out_gemm. ws holds K/V/ctx in bf16 (37.7 MB).
    float* Qf = (float*)d_out;
    char* ws = (char*)d_ws;
    unsigned short* Kb = (unsigned short*)(ws);
    unsigned short* Vb = (unsigned short*)(ws + 12582912);
    unsigned short* Cb = (unsigned short*)(ws + 25165824);

    dim3 g1(64, 6, 3);
    qkv_gemm<<<g1, 256, 0, stream>>>(X, Wq, bq, Wk, bk, Wv, bv, Qf, Kb, Vb);
    dim3 g2(32, 48);
    attn_kernel<<<g2, 128, 0, stream>>>(Qf, Kb, Vb, Cb);
    dim3 g3(64, 6);
    out_gemm<<<g3, 256, 0, stream>>>(Cb, Wo, bo, out);
}

// Round 4
// 168.598 us; speedup vs baseline: 1.5761x; 1.5761x over previous
//
#include <hip/hip_runtime.h>
#include <hip/hip_bf16.h>

#define NHEAD 12
#define HD 64
#define SEQ 2048
#define NB 4
#define HDIM 768
#define MTOT (NB * SEQ)   // 8192

typedef float f32x4 __attribute__((ext_vector_type(4)));
typedef unsigned int u32x4 __attribute__((ext_vector_type(4)));
typedef unsigned short u16x8 __attribute__((ext_vector_type(8)));

__device__ inline unsigned short f2bf(float f) {
    union { float f; unsigned u; } v; v.f = f;
    unsigned r = v.u + 0x7fffu + ((v.u >> 16) & 1u);
    return (unsigned short)(r >> 16);
}
__device__ inline float bf2f(unsigned short u) {
    union { unsigned u; float f; } v; v.u = ((unsigned)u) << 16;
    return v.f;
}

__device__ inline void mfma_bf16(f32x4& c, const u32x4& a, const u32x4& b) {
    asm("v_mfma_f32_16x16x32_bf16 %0, %1, %2, %0" : "+v"(c) : "v"(a), "v"(b));
}

// ---------------------------------------------------------------------------
// Prep 1: X fp32 -> bf16 (8192x768)
// ---------------------------------------------------------------------------
__global__ __launch_bounds__(256) void x_convert(
    const float* __restrict__ X, unsigned short* __restrict__ Xb)
{
    const int i = (blockIdx.x * 256 + threadIdx.x) * 8;
    float4 a = *(const float4*)(X + i);
    float4 b = *(const float4*)(X + i + 4);
    ushort4 wa, wb;
    wa.x = f2bf(a.x); wa.y = f2bf(a.y); wa.z = f2bf(a.z); wa.w = f2bf(a.w);
    wb.x = f2bf(b.x); wb.y = f2bf(b.y); wb.z = f2bf(b.z); wb.w = f2bf(b.w);
    *(ushort4*)(Xb + i) = wa;
    *(ushort4*)(Xb + i + 4) = wb;
}

// ---------------------------------------------------------------------------
// Prep 2: W[k][n] fp32 -> Wt[n][k] bf16 for Wq/Wk/Wv (fused [2304][768]) + Wo
// ---------------------------------------------------------------------------
__global__ __launch_bounds__(256) void w_transpose(
    const float* __restrict__ Wq, const float* __restrict__ Wk,
    const float* __restrict__ Wv, const float* __restrict__ Wo,
    unsigned short* __restrict__ Wt, unsigned short* __restrict__ Wot)
{
    __shared__ __align__(16) unsigned short ts[64][68];  // 136B stride, 8B-aligned
    const int z = blockIdx.z;
    const float* W = (z == 0) ? Wq : (z == 1) ? Wk : (z == 2) ? Wv : Wo;
    unsigned short* D = (z < 3) ? (Wt + (size_t)z * HDIM * HDIM) : Wot;
    const int k0 = blockIdx.x * 64, n0 = blockIdx.y * 64;
    const int t = threadIdx.x;
    const int kr = (t >> 4) * 4;
    const int nc = (t & 15) * 4;
    #pragma unroll
    for (int r = 0; r < 4; r++) {
        float4 v = *(const float4*)(W + (size_t)(k0 + kr + r) * HDIM + n0 + nc);
        ushort4 w;
        w.x = f2bf(v.x); w.y = f2bf(v.y); w.z = f2bf(v.z); w.w = f2bf(v.w);
        *(ushort4*)&ts[kr + r][nc] = w;
    }
    __syncthreads();
    const int nr = t >> 2;
    const int kc = (t & 3) * 16;
    #pragma unroll
    for (int j4 = 0; j4 < 4; j4++) {
        ushort4 w;
        w.x = ts[kc + j4 * 4 + 0][nr];
        w.y = ts[kc + j4 * 4 + 1][nr];
        w.z = ts[kc + j4 * 4 + 2][nr];
        w.w = ts[kc + j4 * 4 + 3][nr];
        *(ushort4*)(D + (size_t)(n0 + nr) * HDIM + k0 + kc + j4 * 4) = w;
    }
}

// ---------------------------------------------------------------------------
// bf16 GEMM: 128x128 tile, BK=64, reg-staged ushort8 loads -> ds_write_b128
// into padded linear LDS [128][72] shorts (row stride 144B). Read pattern is
// the round-1-proven fragment layout. No global_load_lds, no swizzle.
// MODE 0: A=Xb, Bt=Wt[2304][768] -> scatter Q/K/V head-major bf16 (Q scaled).
// MODE 1: A=Cb, Bt=Wot[768][768] -> out fp32 row-major + bias.
// ---------------------------------------------------------------------------
#define LDP 72   // padded row stride in shorts

template<int MODE>
__global__ __launch_bounds__(256) void gemm_kernel(
    const unsigned short* __restrict__ A,
    const unsigned short* __restrict__ Bt,
    const float* __restrict__ bias0, const float* __restrict__ bias1,
    const float* __restrict__ bias2,
    unsigned short* __restrict__ Qb, unsigned short* __restrict__ Kb,
    unsigned short* __restrict__ Vb, float* __restrict__ out)
{
    __shared__ __align__(16) unsigned short As[128 * LDP];
    __shared__ __align__(16) unsigned short Bs[128 * LDP];

    const int t = threadIdx.x;
    const int lane = t & 63;
    const int wid = t >> 6;
    const int wm = wid >> 1, wn = wid & 1;
    const int g = lane >> 4, r16 = lane & 15;

    const int m0 = blockIdx.x * 128;
    const int n0 = blockIdx.y * 128;

    f32x4 acc[4][4] = {};

    for (int k0 = 0; k0 < HDIM; k0 += 64) {
        // issue global loads early (16B each; 8 chunks/row, 4 rows' worth/thread)
        u16x8 ra[4], rb[4];
        #pragma unroll
        for (int i = 0; i < 4; i++) {
            const int f = i * 256 + t;          // 0..1023
            const int row = f >> 3, c8 = f & 7; // c8: 16B chunk within row
            ra[i] = *(const u16x8*)(A  + (size_t)(m0 + row) * HDIM + k0 + c8 * 8);
            rb[i] = *(const u16x8*)(Bt + (size_t)(n0 + row) * HDIM + k0 + c8 * 8);
        }
        __syncthreads();   // previous iteration's compute done
        #pragma unroll
        for (int i = 0; i < 4; i++) {
            const int f = i * 256 + t;
            const int row = f >> 3, c8 = f & 7;
            *(u16x8*)(As + row * LDP + c8 * 8) = ra[i];
            *(u16x8*)(Bs + row * LDP + c8 * 8) = rb[i];
        }
        __syncthreads();   // LDS tile visible to all waves

        #pragma unroll
        for (int ks = 0; ks < 2; ks++) {
            u32x4 af[4], bf[4];
            #pragma unroll
            for (int fm = 0; fm < 4; fm++) {
                const unsigned short* p = As + (wm * 64 + fm * 16 + r16) * LDP + ks * 32;
                uint2 lo = *(const uint2*)(p + 4 * g);
                uint2 hi = *(const uint2*)(p + 16 + 4 * g);
                u32x4 a; a.x = lo.x; a.y = lo.y; a.z = hi.x; a.w = hi.y;
                af[fm] = a;
            }
            #pragma unroll
            for (int fn = 0; fn < 4; fn++) {
                const unsigned short* p = Bs + (wn * 64 + fn * 16 + r16) * LDP + ks * 32;
                uint2 lo = *(const uint2*)(p + 4 * g);
                uint2 hi = *(const uint2*)(p + 16 + 4 * g);
                u32x4 b; b.x = lo.x; b.y = lo.y; b.z = hi.x; b.w = hi.y;
                bf[fn] = b;
            }
            #pragma unroll
            for (int fm = 0; fm < 4; fm++)
                #pragma unroll
                for (int fn = 0; fn < 4; fn++)
                    mfma_bf16(acc[fm][fn], af[fm], bf[fn]);
        }
    }

    if (MODE == 0) {
        const int z = n0 / HDIM;   // uniform per block (768 % 128 == 0)
        const float* bias = (z == 0) ? bias0 : (z == 1) ? bias1 : bias2;
        const float scale = (z == 0) ? 0.125f : 1.0f;
        unsigned short* dst = (z == 0) ? Qb : (z == 1) ? Kb : Vb;
        #pragma unroll
        for (int fm = 0; fm < 4; fm++) {
            #pragma unroll
            for (int fn = 0; fn < 4; fn++) {
                const int coll = (n0 - z * HDIM) + wn * 64 + fn * 16 + r16;
                const float bc = bias[coll];
                const int h = coll >> 6, d = coll & 63;
                #pragma unroll
                for (int r = 0; r < 4; r++) {
                    const int m = m0 + wm * 64 + fm * 16 + 4 * g + r;
                    const int b = m >> 11, s = m & (SEQ - 1);
                    const size_t idx = (((size_t)b * NHEAD + h) * SEQ + s) * HD + d;
                    dst[idx] = f2bf((acc[fm][fn][r] + bc) * scale);
                }
            }
        }
    } else {
        #pragma unroll
        for (int fm = 0; fm < 4; fm++) {
            #pragma unroll
            for (int fn = 0; fn < 4; fn++) {
                const int col = n0 + wn * 64 + fn * 16 + r16;
                const float bc = bias0[col];
                #pragma unroll
                for (int r = 0; r < 4; r++) {
                    const int m = m0 + wm * 64 + fm * 16 + 4 * g + r;
                    out[(size_t)m * HDIM + col] = acc[fm][fn][r] + bc;
                }
            }
        }
    }
}

// ---------------------------------------------------------------------------
// Banded attention. One block = one (b*h, 64-query tile). 128 threads:
// 2 threads per query. Window |i-j| <= 32 -> 65 keys/query. Q/K/V all bf16.
// ---------------------------------------------------------------------------
__global__ __launch_bounds__(128) void attn_kernel(
    const unsigned short* __restrict__ Qb, const unsigned short* __restrict__ Kb,
    const unsigned short* __restrict__ Vb, unsigned short* __restrict__ Cb)
{
    __shared__ __align__(16) unsigned short Ks[128][68];
    __shared__ __align__(16) unsigned short Vs[128][68];
    __shared__ float Sc[64][67];

    const int t = threadIdx.x;
    const int q0 = blockIdx.x * 64;
    const int bh = blockIdx.y;
    const int b = bh / NHEAD, h = bh % NHEAD;
    const size_t base = (size_t)bh * SEQ * HD;
    const int kstart = q0 - 32;

    #pragma unroll
    for (int i = 0; i < 16; i++) {
        int f = i * 128 + t;
        int row = f >> 4, c4 = f & 15;
        int j = kstart + row;
        ushort4 kv = make_ushort4(0, 0, 0, 0);
        ushort4 vv = make_ushort4(0, 0, 0, 0);
        if (j >= 0 && j < SEQ) {
            kv = *(const ushort4*)(Kb + base + (size_t)j * HD + c4 * 4);
            vv = *(const ushort4*)(Vb + base + (size_t)j * HD + c4 * 4);
        }
        *(ushort4*)&Ks[row][c4 * 4] = kv;
        *(ushort4*)&Vs[row][c4 * 4] = vv;
    }

    const int q = t >> 1;
    const int half = t & 1;
    const int i_glob = q0 + q;

    float qr[64];
    #pragma unroll
    for (int d4 = 0; d4 < 16; d4++) {
        ushort4 v = *(const ushort4*)(Qb + base + (size_t)i_glob * HD + d4 * 4);
        qr[d4 * 4 + 0] = bf2f(v.x); qr[d4 * 4 + 1] = bf2f(v.y);
        qr[d4 * 4 + 2] = bf2f(v.z); qr[d4 * 4 + 3] = bf2f(v.w);
    }
    __syncthreads();

    const int jj0 = half ? 33 : 0;
    const int jjn = half ? 32 : 33;
    for (int u = 0; u < jjn; u++) {
        int jj = jj0 + u;
        int jg = i_glob - 32 + jj;
        float s = -1e30f;
        if (jg >= 0 && jg < SEQ) {
            int row = q + jj;
            float a = 0.f;
            #pragma unroll
            for (int d4 = 0; d4 < 16; d4++) {
                ushort4 kv = *(const ushort4*)&Ks[row][d4 * 4];
                a += qr[d4 * 4 + 0] * bf2f(kv.x) + qr[d4 * 4 + 1] * bf2f(kv.y)
                   + qr[d4 * 4 + 2] * bf2f(kv.z) + qr[d4 * 4 + 3] * bf2f(kv.w);
            }
            s = a;  // Q already carries 1/sqrt(HD)
        }
        Sc[q][jj] = s;
    }
    __syncthreads();

    if (t < 64) {
        float m = -1e30f;
        for (int jj = 0; jj < 65; jj++) m = fmaxf(m, Sc[t][jj]);
        float sum = 0.f;
        for (int jj = 0; jj < 65; jj++) {
            float e = __expf(Sc[t][jj] - m);
            Sc[t][jj] = e;
            sum += e;
        }
        float inv = 1.f / sum;
        for (int jj = 0; jj < 65; jj++) Sc[t][jj] *= inv;
    }
    __syncthreads();

    float ctx[32] = {};
    for (int jj = 0; jj < 65; jj++) {
        float p = Sc[q][jj];
        int row = q + jj;
        #pragma unroll
        for (int d4 = 0; d4 < 8; d4++) {
            ushort4 vv = *(const ushort4*)&Vs[row][half * 32 + d4 * 4];
            ctx[d4 * 4 + 0] += p * bf2f(vv.x);
            ctx[d4 * 4 + 1] += p * bf2f(vv.y);
            ctx[d4 * 4 + 2] += p * bf2f(vv.z);
            ctx[d4 * 4 + 3] += p * bf2f(vv.w);
        }
    }
    unsigned short* dst = Cb + (((size_t)b * SEQ + i_glob) * NHEAD + h) * HD + half * 32;
    #pragma unroll
    for (int d4 = 0; d4 < 8; d4++) {
        ushort4 w;
        w.x = f2bf(ctx[d4 * 4 + 0]); w.y = f2bf(ctx[d4 * 4 + 1]);
        w.z = f2bf(ctx[d4 * 4 + 2]); w.w = f2bf(ctx[d4 * 4 + 3]);
        *(ushort4*)(dst + d4 * 4) = w;
    }
}

// ---------------------------------------------------------------------------
extern "C" void kernel_launch(void* const* d_in, const int* in_sizes, int n_in,
                              void* d_out, int out_size, void* d_ws, size_t ws_size,
                              hipStream_t stream)
{
    const float* X  = (const float*)d_in[0];
    const float* Wq = (const float*)d_in[1];
    const float* bq = (const float*)d_in[2];
    const float* Wk = (const float*)d_in[3];
    const float* bk = (const float*)d_in[4];
    const float* Wv = (const float*)d_in[5];
    const float* bv = (const float*)d_in[6];
    const float* Wo = (const float*)d_in[7];
    const float* bo = (const float*)d_in[8];
    float* out = (float*)d_out;

    // Buffer plan (all dead-before-overwrite, stream-ordered):
    //   ws:    [0)        Xb bf16 12.58MB  (consumed by qkv gemm, then reused as Cb)
    //          [12.58M)   Vb bf16 12.58MB
    //          [25.17M)   Wt bf16 [2304][768] 3.54MB
    //          [28.70M)   Wot bf16 [768][768] 1.18MB        total 29.9MB
    //   d_out: [0)        Qb bf16 12.58MB  (scaled by 1/8)
    //          [12.58M)   Kb bf16 12.58MB  -> both overwritten by final out
    char* ws = (char*)d_ws;
    unsigned short* Xb  = (unsigned short*)ws;
    unsigned short* Cb  = Xb;   // alias: Xb dead once qkv gemm finishes
    unsigned short* Vb  = (unsigned short*)(ws + 12582912);
    unsigned short* Wt  = (unsigned short*)(ws + 25165824);
    unsigned short* Wot = (unsigned short*)(ws + 28704768);
    unsigned short* Qb  = (unsigned short*)d_out;
    unsigned short* Kb  = (unsigned short*)((char*)d_out + 12582912);

    x_convert<<<dim3(3072), 256, 0, stream>>>(X, Xb);
    w_transpose<<<dim3(12, 12, 4), 256, 0, stream>>>(Wq, Wk, Wv, Wo, Wt, Wot);
    gemm_kernel<0><<<dim3(64, 18), 256, 0, stream>>>(Xb, Wt, bq, bk, bv, Qb, Kb, Vb, nullptr);
    attn_kernel<<<dim3(32, 48), 128, 0, stream>>>(Qb, Kb, Vb, Cb);
    gemm_kernel<1><<<dim3(64, 6), 256, 0, stream>>>(Cb, Wot, bo, nullptr, nullptr,
                                                    nullptr, nullptr, nullptr, out);
}

// Round 6
// 143.152 us; speedup vs baseline: 1.8563x; 1.1778x over previous
//
#include <hip/hip_runtime.h>
#include <hip/hip_bf16.h>

#define NHEAD 12
#define HD 64
#define SEQ 2048
#define NB 4
#define HDIM 768
#define MTOT (NB * SEQ)   // 8192

typedef float f32x4 __attribute__((ext_vector_type(4)));
typedef short s16x8 __attribute__((ext_vector_type(8)));
typedef unsigned short u16x8 __attribute__((ext_vector_type(8)));

__device__ inline unsigned short f2bf(float f) {
    union { float f; unsigned u; } v; v.f = f;
    unsigned r = v.u + 0x7fffu + ((v.u >> 16) & 1u);
    return (unsigned short)(r >> 16);
}
__device__ inline float bf2f(unsigned short u) {
    union { unsigned u; float f; } v; v.u = ((unsigned)u) << 16;
    return v.f;
}
__device__ inline unsigned pack_bf2(float a, float b) {
    return (unsigned)f2bf(a) | ((unsigned)f2bf(b) << 16);
}
__device__ inline s16x8 mk_frag(uint2 lo, uint2 hi) {
    union { unsigned u[4]; s16x8 v; } r;
    r.u[0] = lo.x; r.u[1] = lo.y; r.u[2] = hi.x; r.u[3] = hi.y;
    return r.v;
}

#define MFMA(acc, a, b) \
    acc = __builtin_amdgcn_mfma_f32_16x16x32_bf16((a), (b), (acc), 0, 0, 0)

// ---------------------------------------------------------------------------
// Prep 1: X fp32 -> bf16 (8192x768)
// ---------------------------------------------------------------------------
__global__ __launch_bounds__(256) void x_convert(
    const float* __restrict__ X, unsigned short* __restrict__ Xb)
{
    const int i = (blockIdx.x * 256 + threadIdx.x) * 8;
    float4 a = *(const float4*)(X + i);
    float4 b = *(const float4*)(X + i + 4);
    ushort4 wa, wb;
    wa.x = f2bf(a.x); wa.y = f2bf(a.y); wa.z = f2bf(a.z); wa.w = f2bf(a.w);
    wb.x = f2bf(b.x); wb.y = f2bf(b.y); wb.z = f2bf(b.z); wb.w = f2bf(b.w);
    *(ushort4*)(Xb + i) = wa;
    *(ushort4*)(Xb + i + 4) = wb;
}

// ---------------------------------------------------------------------------
// Prep 2: W[k][n] fp32 -> Wt[n][k] bf16 for Wq/Wk/Wv (fused [2304][768]) + Wo
// ---------------------------------------------------------------------------
__global__ __launch_bounds__(256) void w_transpose(
    const float* __restrict__ Wq, const float* __restrict__ Wk,
    const float* __restrict__ Wv, const float* __restrict__ Wo,
    unsigned short* __restrict__ Wt, unsigned short* __restrict__ Wot)
{
    __shared__ __align__(16) unsigned short ts[64][68];  // 136B stride, 8B-aligned
    const int z = blockIdx.z;
    const float* W = (z == 0) ? Wq : (z == 1) ? Wk : (z == 2) ? Wv : Wo;
    unsigned short* D = (z < 3) ? (Wt + (size_t)z * HDIM * HDIM) : Wot;
    const int k0 = blockIdx.x * 64, n0 = blockIdx.y * 64;
    const int t = threadIdx.x;
    const int kr = (t >> 4) * 4;
    const int nc = (t & 15) * 4;
    #pragma unroll
    for (int r = 0; r < 4; r++) {
        float4 v = *(const float4*)(W + (size_t)(k0 + kr + r) * HDIM + n0 + nc);
        ushort4 w;
        w.x = f2bf(v.x); w.y = f2bf(v.y); w.z = f2bf(v.z); w.w = f2bf(v.w);
        *(ushort4*)&ts[kr + r][nc] = w;
    }
    __syncthreads();
    const int nr = t >> 2;
    const int kc = (t & 3) * 16;
    #pragma unroll
    for (int j4 = 0; j4 < 4; j4++) {
        ushort4 w;
        w.x = ts[kc + j4 * 4 + 0][nr];
        w.y = ts[kc + j4 * 4 + 1][nr];
        w.z = ts[kc + j4 * 4 + 2][nr];
        w.w = ts[kc + j4 * 4 + 3][nr];
        *(ushort4*)(D + (size_t)(n0 + nr) * HDIM + k0 + kc + j4 * 4) = w;
    }
}

// ---------------------------------------------------------------------------
// bf16 GEMM: 128x128 tile, BK=64, reg-staged ushort8 loads -> ds_write_b128
// into padded linear LDS [128][72] shorts. (R4-proven structure, builtin MFMA.)
// MODE 0: A=Xb, Bt=Wt[2304][768] -> Q/K head-major bf16 (Q scaled), V
//         TRANSPOSED per head: Vt[bh][d][s].
// MODE 1: A=Cb, Bt=Wot[768][768] -> out fp32 row-major + bias.
// ---------------------------------------------------------------------------
#define LDP 72   // padded row stride in shorts

template<int MODE>
__global__ __launch_bounds__(256) void gemm_kernel(
    const unsigned short* __restrict__ A,
    const unsigned short* __restrict__ Bt,
    const float* __restrict__ bias0, const float* __restrict__ bias1,
    const float* __restrict__ bias2,
    unsigned short* __restrict__ Qb, unsigned short* __restrict__ Kb,
    unsigned short* __restrict__ Vb, float* __restrict__ out)
{
    __shared__ __align__(16) unsigned short As[128 * LDP];
    __shared__ __align__(16) unsigned short Bs[128 * LDP];

    const int t = threadIdx.x;
    const int lane = t & 63;
    const int wid = t >> 6;
    const int wm = wid >> 1, wn = wid & 1;
    const int g = lane >> 4, r16 = lane & 15;

    const int m0 = blockIdx.x * 128;
    const int n0 = blockIdx.y * 128;

    f32x4 acc[4][4] = {};

    for (int k0 = 0; k0 < HDIM; k0 += 64) {
        u16x8 ra[4], rb[4];
        #pragma unroll
        for (int i = 0; i < 4; i++) {
            const int f = i * 256 + t;
            const int row = f >> 3, c8 = f & 7;
            ra[i] = *(const u16x8*)(A  + (size_t)(m0 + row) * HDIM + k0 + c8 * 8);
            rb[i] = *(const u16x8*)(Bt + (size_t)(n0 + row) * HDIM + k0 + c8 * 8);
        }
        __syncthreads();
        #pragma unroll
        for (int i = 0; i < 4; i++) {
            const int f = i * 256 + t;
            const int row = f >> 3, c8 = f & 7;
            *(u16x8*)(As + row * LDP + c8 * 8) = ra[i];
            *(u16x8*)(Bs + row * LDP + c8 * 8) = rb[i];
        }
        __syncthreads();

        #pragma unroll
        for (int ks = 0; ks < 2; ks++) {
            s16x8 af[4], bf[4];
            #pragma unroll
            for (int fm = 0; fm < 4; fm++) {
                const unsigned short* p = As + (wm * 64 + fm * 16 + r16) * LDP + ks * 32;
                af[fm] = mk_frag(*(const uint2*)(p + 4 * g),
                                 *(const uint2*)(p + 16 + 4 * g));
            }
            #pragma unroll
            for (int fn = 0; fn < 4; fn++) {
                const unsigned short* p = Bs + (wn * 64 + fn * 16 + r16) * LDP + ks * 32;
                bf[fn] = mk_frag(*(const uint2*)(p + 4 * g),
                                 *(const uint2*)(p + 16 + 4 * g));
            }
            #pragma unroll
            for (int fm = 0; fm < 4; fm++)
                #pragma unroll
                for (int fn = 0; fn < 4; fn++)
                    MFMA(acc[fm][fn], af[fm], bf[fn]);
        }
    }

    if (MODE == 0) {
        const int z = n0 / HDIM;   // uniform per block
        const float* bias = (z == 0) ? bias0 : (z == 1) ? bias1 : bias2;
        const float scale = (z == 0) ? 0.125f : 1.0f;
        unsigned short* dst = (z == 0) ? Qb : (z == 1) ? Kb : Vb;
        #pragma unroll
        for (int fm = 0; fm < 4; fm++) {
            #pragma unroll
            for (int fn = 0; fn < 4; fn++) {
                const int coll = (n0 - z * HDIM) + wn * 64 + fn * 16 + r16;
                const float bc = bias[coll];
                const int h = coll >> 6, d = coll & 63;
                #pragma unroll
                for (int r = 0; r < 4; r++) {
                    const int m = m0 + wm * 64 + fm * 16 + 4 * g + r;
                    const int b = m >> 11, s = m & (SEQ - 1);
                    const size_t idx = (z == 2)
                        ? ((((size_t)b * NHEAD + h) * HD + d) * SEQ + s)     // V^T
                        : ((((size_t)b * NHEAD + h) * SEQ + s) * HD + d);    // Q,K
                    dst[idx] = f2bf((acc[fm][fn][r] + bc) * scale);
                }
            }
        }
    } else {
        #pragma unroll
        for (int fm = 0; fm < 4; fm++) {
            #pragma unroll
            for (int fn = 0; fn < 4; fn++) {
                const int col = n0 + wn * 64 + fn * 16 + r16;
                const float bc = bias0[col];
                #pragma unroll
                for (int r = 0; r < 4; r++) {
                    const int m = m0 + wm * 64 + fm * 16 + 4 * g + r;
                    out[(size_t)m * HDIM + col] = acc[fm][fn][r] + bc;
                }
            }
        }
    }
}

// ---------------------------------------------------------------------------
// MFMA banded attention (R5 structure, builtin MFMA). One block =
// (bh, 64-query tile), 4 waves; wave wq owns queries wq*16..wq*16+15.
// QK^T swapped: S^T[key][q] = mfma(K, Q); in-register softmax (2 shfl_xor);
// P normalized pre-pack; PV = mfma(P, V^T-frags).
// ---------------------------------------------------------------------------
__global__ __launch_bounds__(256) void attn_mfma(
    const unsigned short* __restrict__ Qb, const unsigned short* __restrict__ Kb,
    const unsigned short* __restrict__ Vtg, unsigned short* __restrict__ Cb)
{
    __shared__ __align__(16) unsigned short Ks[128][72];   // [key][d]
    __shared__ __align__(16) unsigned short Qs[64][72];    // [q][d]
    __shared__ __align__(16) unsigned short Vs[64][136];   // [d][key]

    const int t = threadIdx.x;
    const int lane = t & 63;
    const int wq = t >> 6;                 // wave's query quarter (0..3)
    const int g = lane >> 4, r16 = lane & 15;
    const int q0 = blockIdx.x * 64;
    const int bh = blockIdx.y;
    const int b = bh / NHEAD, h = bh - b * NHEAD;
    const size_t base  = (size_t)bh * SEQ * HD;
    const size_t vbase = (size_t)bh * HD * SEQ;
    const int kstart = q0 - 32;
    const bool interior = (kstart >= 0) && (kstart + 127 < SEQ);

    // ---- stage K [128][64]
    {
        const int row = t >> 1, c0 = (t & 1) * 32;
        const int s = kstart + row;
        if (s >= 0 && s < SEQ) {
            const unsigned short* src = Kb + base + (size_t)s * HD + c0;
            #pragma unroll
            for (int j = 0; j < 4; j++)
                *(u16x8*)&Ks[row][c0 + 8 * j] = *(const u16x8*)(src + 8 * j);
        } else {
            const u16x8 z = {};
            #pragma unroll
            for (int j = 0; j < 4; j++)
                *(u16x8*)&Ks[row][c0 + 8 * j] = z;
        }
    }
    // ---- stage Q [64][64]
    {
        const int row = t >> 2, c0 = (t & 3) * 16;
        const unsigned short* src = Qb + base + (size_t)(q0 + row) * HD + c0;
        *(u16x8*)&Qs[row][c0] = *(const u16x8*)src;
        *(u16x8*)&Qs[row][c0 + 8] = *(const u16x8*)(src + 8);
    }
    // ---- stage V^T [64][128]
    {
        const int row = t >> 2, c0 = (t & 3) * 32;
        const unsigned short* src = Vtg + vbase + (size_t)row * SEQ + kstart + c0;
        if (interior) {
            #pragma unroll
            for (int j = 0; j < 4; j++)
                *(u16x8*)&Vs[row][c0 + 8 * j] = *(const u16x8*)(src + 8 * j);
        } else {
            for (int e = 0; e < 32; e++) {
                const int s = kstart + c0 + e;
                Vs[row][c0 + e] = (s >= 0 && s < SEQ) ? src[e] : (unsigned short)0;
            }
        }
    }
    __syncthreads();

    // ---- QK^T (swapped): sacc[mf] = S^T rows 16mf+4g+0..3, col q=r16
    s16x8 qf[2];
    {
        const unsigned short* p = &Qs[wq * 16 + r16][0];
        #pragma unroll
        for (int c = 0; c < 2; c++)
            qf[c] = mk_frag(*(const uint2*)(p + c * 32 + 4 * g),
                            *(const uint2*)(p + c * 32 + 16 + 4 * g));
    }
    f32x4 sacc[8] = {};
    #pragma unroll
    for (int mf = 0; mf < 8; mf++) {
        const unsigned short* p = &Ks[mf * 16 + r16][0];
        #pragma unroll
        for (int c = 0; c < 2; c++) {
            s16x8 kf = mk_frag(*(const uint2*)(p + c * 32 + 4 * g),
                               *(const uint2*)(p + c * 32 + 16 + 4 * g));
            MFMA(sacc[mf], kf, qf[c]);
        }
    }

    // ---- band mask + in-register softmax (query = wq*16 + r16)
    const int q_local = wq * 16 + r16;
    float mx = -1e30f;
    #pragma unroll
    for (int mf = 0; mf < 8; mf++) {
        #pragma unroll
        for (int r = 0; r < 4; r++) {
            const int key = mf * 16 + 4 * g + r;
            const int rel = key - q_local;            // j-i+32, valid [0,64]
            const int sg = kstart + key;
            const bool ok = (rel >= 0) && (rel <= 64) && (sg >= 0) && (sg < SEQ);
            const float v = ok ? sacc[mf][r] : -1e30f;
            sacc[mf][r] = v;
            mx = fmaxf(mx, v);
        }
    }
    mx = fmaxf(mx, __shfl_xor(mx, 16));
    mx = fmaxf(mx, __shfl_xor(mx, 32));
    float l = 0.f;
    #pragma unroll
    for (int mf = 0; mf < 8; mf++) {
        #pragma unroll
        for (int r = 0; r < 4; r++) {
            const float e = __expf(sacc[mf][r] - mx);
            sacc[mf][r] = e;
            l += e;
        }
    }
    l += __shfl_xor(l, 16);
    l += __shfl_xor(l, 32);
    const float inv = 1.f / l;

    // ---- pack normalized P -> bf16 A-operand frags (key chunks of 32)
    s16x8 pf[4];
    #pragma unroll
    for (int c = 0; c < 4; c++) {
        union { unsigned u[4]; s16x8 v; } pv;
        pv.u[0] = pack_bf2(sacc[2 * c][0] * inv, sacc[2 * c][1] * inv);
        pv.u[1] = pack_bf2(sacc[2 * c][2] * inv, sacc[2 * c][3] * inv);
        pv.u[2] = pack_bf2(sacc[2 * c + 1][0] * inv, sacc[2 * c + 1][1] * inv);
        pv.u[3] = pack_bf2(sacc[2 * c + 1][2] * inv, sacc[2 * c + 1][3] * inv);
        pf[c] = pv.v;
    }

    // ---- PV: ctx[q][d] = P(A) x V^T(B); cacc[nf] rows q=4g+r, col d=16nf+r16
    f32x4 cacc[4] = {};
    #pragma unroll
    for (int nf = 0; nf < 4; nf++) {
        const unsigned short* p = &Vs[nf * 16 + r16][0];
        #pragma unroll
        for (int c = 0; c < 4; c++) {
            s16x8 vf = mk_frag(*(const uint2*)(p + c * 32 + 4 * g),
                               *(const uint2*)(p + c * 32 + 16 + 4 * g));
            MFMA(cacc[nf], pf[c], vf);
        }
    }

    // ---- write ctx bf16 [b][s][h][d]
    #pragma unroll
    for (int nf = 0; nf < 4; nf++) {
        #pragma unroll
        for (int r = 0; r < 4; r++) {
            const int ql = wq * 16 + 4 * g + r;
            const int d = nf * 16 + r16;
            Cb[(((size_t)b * SEQ + q0 + ql) * NHEAD + h) * HD + d] = f2bf(cacc[nf][r]);
        }
    }
}

// ---------------------------------------------------------------------------
extern "C" void kernel_launch(void* const* d_in, const int* in_sizes, int n_in,
                              void* d_out, int out_size, void* d_ws, size_t ws_size,
                              hipStream_t stream)
{
    const float* X  = (const float*)d_in[0];
    const float* Wq = (const float*)d_in[1];
    const float* bq = (const float*)d_in[2];
    const float* Wk = (const float*)d_in[3];
    const float* bk = (const float*)d_in[4];
    const float* Wv = (const float*)d_in[5];
    const float* bv = (const float*)d_in[6];
    const float* Wo = (const float*)d_in[7];
    const float* bo = (const float*)d_in[8];
    float* out = (float*)d_out;

    // Buffer plan:
    //   ws:    [0)        Xb bf16 12.58MB  (reused as Cb after qkv gemm)
    //          [12.58M)   Vt bf16 12.58MB  ([bh][d][s] transposed)
    //          [25.17M)   Wt bf16 [2304][768] 3.54MB
    //          [28.70M)   Wot bf16 [768][768] 1.18MB
    //   d_out: [0) Qb 12.58MB, [12.58M) Kb 12.58MB -> overwritten by final out
    char* ws = (char*)d_ws;
    unsigned short* Xb  = (unsigned short*)ws;
    unsigned short* Cb  = Xb;
    unsigned short* Vt  = (unsigned short*)(ws + 12582912);
    unsigned short* Wtp = (unsigned short*)(ws + 25165824);
    unsigned short* Wot = (unsigned short*)(ws + 28704768);
    unsigned short* Qb  = (unsigned short*)d_out;
    unsigned short* Kb  = (unsigned short*)((char*)d_out + 12582912);

    x_convert<<<dim3(3072), 256, 0, stream>>>(X, Xb);
    w_transpose<<<dim3(12, 12, 4), 256, 0, stream>>>(Wq, Wk, Wv, Wo, Wtp, Wot);
    gemm_kernel<0><<<dim3(64, 18), 256, 0, stream>>>(Xb, Wtp, bq, bk, bv, Qb, Kb, Vt, nullptr);
    attn_mfma<<<dim3(32, 48), 256, 0, stream>>>(Qb, Kb, Vt, Cb);
    gemm_kernel<1><<<dim3(64, 6), 256, 0, stream>>>(Cb, Wot, bo, nullptr, nullptr,
                                                    nullptr, nullptr, nullptr, out);
}

// Round 7
// 122.072 us; speedup vs baseline: 2.1769x; 1.1727x over previous
//
#include <hip/hip_runtime.h>
#include <hip/hip_bf16.h>

#define NHEAD 12
#define HD 64
#define SEQ 2048
#define NB 4
#define HDIM 768
#define MTOT (NB * SEQ)   // 8192

typedef float f32x4 __attribute__((ext_vector_type(4)));
typedef float f32x16 __attribute__((ext_vector_type(16)));
typedef short s16x8 __attribute__((ext_vector_type(8)));
typedef unsigned short u16x8 __attribute__((ext_vector_type(8)));

__device__ inline unsigned short f2bf(float f) {
    union { float f; unsigned u; } v; v.f = f;
    unsigned r = v.u + 0x7fffu + ((v.u >> 16) & 1u);
    return (unsigned short)(r >> 16);
}
__device__ inline float bf2f(unsigned short u) {
    union { unsigned u; float f; } v; v.u = ((unsigned)u) << 16;
    return v.f;
}
__device__ inline unsigned pack_bf2(float a, float b) {
    return (unsigned)f2bf(a) | ((unsigned)f2bf(b) << 16);
}
__device__ inline s16x8 mk_frag(uint2 lo, uint2 hi) {
    union { unsigned u[4]; s16x8 v; } r;
    r.u[0] = lo.x; r.u[1] = lo.y; r.u[2] = hi.x; r.u[3] = hi.y;
    return r.v;
}

#define MFMA(acc, a, b) \
    acc = __builtin_amdgcn_mfma_f32_16x16x32_bf16((a), (b), (acc), 0, 0, 0)
#define MFMA32(acc, a, b) \
    acc = __builtin_amdgcn_mfma_f32_32x32x16_bf16((a), (b), (acc), 0, 0, 0)

// ---------------------------------------------------------------------------
// Prep 1: X fp32 -> bf16 (8192x768)
// ---------------------------------------------------------------------------
__global__ __launch_bounds__(256) void x_convert(
    const float* __restrict__ X, unsigned short* __restrict__ Xb)
{
    const int i = (blockIdx.x * 256 + threadIdx.x) * 8;
    float4 a = *(const float4*)(X + i);
    float4 b = *(const float4*)(X + i + 4);
    ushort4 wa, wb;
    wa.x = f2bf(a.x); wa.y = f2bf(a.y); wa.z = f2bf(a.z); wa.w = f2bf(a.w);
    wb.x = f2bf(b.x); wb.y = f2bf(b.y); wb.z = f2bf(b.z); wb.w = f2bf(b.w);
    *(ushort4*)(Xb + i) = wa;
    *(ushort4*)(Xb + i + 4) = wb;
}

// ---------------------------------------------------------------------------
// Prep 2: W[k][n] fp32 -> Wt[n][k] bf16 for Wq/Wk/Wv (fused [2304][768]) + Wo
// ---------------------------------------------------------------------------
__global__ __launch_bounds__(256) void w_transpose(
    const float* __restrict__ Wq, const float* __restrict__ Wk,
    const float* __restrict__ Wv, const float* __restrict__ Wo,
    unsigned short* __restrict__ Wt, unsigned short* __restrict__ Wot)
{
    __shared__ __align__(16) unsigned short ts[64][68];  // 136B stride, 8B-aligned
    const int z = blockIdx.z;
    const float* W = (z == 0) ? Wq : (z == 1) ? Wk : (z == 2) ? Wv : Wo;
    unsigned short* D = (z < 3) ? (Wt + (size_t)z * HDIM * HDIM) : Wot;
    const int k0 = blockIdx.x * 64, n0 = blockIdx.y * 64;
    const int t = threadIdx.x;
    const int kr = (t >> 4) * 4;
    const int nc = (t & 15) * 4;
    #pragma unroll
    for (int r = 0; r < 4; r++) {
        float4 v = *(const float4*)(W + (size_t)(k0 + kr + r) * HDIM + n0 + nc);
        ushort4 w;
        w.x = f2bf(v.x); w.y = f2bf(v.y); w.z = f2bf(v.z); w.w = f2bf(v.w);
        *(ushort4*)&ts[kr + r][nc] = w;
    }
    __syncthreads();
    const int nr = t >> 2;
    const int kc = (t & 3) * 16;
    #pragma unroll
    for (int j4 = 0; j4 < 4; j4++) {
        ushort4 w;
        w.x = ts[kc + j4 * 4 + 0][nr];
        w.y = ts[kc + j4 * 4 + 1][nr];
        w.z = ts[kc + j4 * 4 + 2][nr];
        w.w = ts[kc + j4 * 4 + 3][nr];
        *(ushort4*)(D + (size_t)(n0 + nr) * HDIM + k0 + kc + j4 * 4) = w;
    }
}

// ---------------------------------------------------------------------------
// bf16 GEMM: 128x128 tile, BK=64, reg-staged ushort8 loads -> ds_write_b128
// into padded linear LDS [128][72] shorts. Compute: 32x32x16 MFMA, 2x2 frags
// per wave, single contiguous ds_read_b128 per fragment (same-k-map-on-both-
// operands makes any k-permutation cancel).
// MODE 0: A=Xb, Bt=Wt[2304][768] -> Q/K head-major bf16 (Q scaled), V
//         TRANSPOSED per head: Vt[bh][d][s].
// MODE 1: A=Cb, Bt=Wot[768][768] -> out fp32 row-major + bias.
// ---------------------------------------------------------------------------
#define LDP 72   // padded row stride in shorts (144B: 16B-aligned rows)

template<int MODE>
__global__ __launch_bounds__(256) void gemm_kernel(
    const unsigned short* __restrict__ A,
    const unsigned short* __restrict__ Bt,
    const float* __restrict__ bias0, const float* __restrict__ bias1,
    const float* __restrict__ bias2,
    unsigned short* __restrict__ Qb, unsigned short* __restrict__ Kb,
    unsigned short* __restrict__ Vb, float* __restrict__ out)
{
    __shared__ __align__(16) unsigned short As[128 * LDP];
    __shared__ __align__(16) unsigned short Bs[128 * LDP];

    const int t = threadIdx.x;
    const int lane = t & 63;
    const int wid = t >> 6;
    const int wm = wid >> 1, wn = wid & 1;
    const int l31 = lane & 31;
    const int lh = lane >> 5;

    const int m0 = blockIdx.x * 128;
    const int n0 = blockIdx.y * 128;

    f32x16 acc[2][2] = {};

    for (int k0 = 0; k0 < HDIM; k0 += 64) {
        u16x8 ra[4], rb[4];
        #pragma unroll
        for (int i = 0; i < 4; i++) {
            const int f = i * 256 + t;
            const int row = f >> 3, c8 = f & 7;
            ra[i] = *(const u16x8*)(A  + (size_t)(m0 + row) * HDIM + k0 + c8 * 8);
            rb[i] = *(const u16x8*)(Bt + (size_t)(n0 + row) * HDIM + k0 + c8 * 8);
        }
        __syncthreads();
        #pragma unroll
        for (int i = 0; i < 4; i++) {
            const int f = i * 256 + t;
            const int row = f >> 3, c8 = f & 7;
            *(u16x8*)(As + row * LDP + c8 * 8) = ra[i];
            *(u16x8*)(Bs + row * LDP + c8 * 8) = rb[i];
        }
        __syncthreads();

        #pragma unroll
        for (int kv = 0; kv < 4; kv++) {   // 4 k-slices of 16
            const int co = kv * 16 + lh * 8;
            s16x8 a0 = *(const s16x8*)(As + (wm * 64 +      l31) * LDP + co);
            s16x8 a1 = *(const s16x8*)(As + (wm * 64 + 32 + l31) * LDP + co);
            s16x8 b0 = *(const s16x8*)(Bs + (wn * 64 +      l31) * LDP + co);
            s16x8 b1 = *(const s16x8*)(Bs + (wn * 64 + 32 + l31) * LDP + co);
            MFMA32(acc[0][0], a0, b0);
            MFMA32(acc[0][1], a0, b1);
            MFMA32(acc[1][0], a1, b0);
            MFMA32(acc[1][1], a1, b1);
        }
    }

    // C/D map (verified): col = lane&31, row = (reg&3) + 8*(reg>>2) + 4*(lane>>5)
    if (MODE == 0) {
        const int z = n0 / HDIM;   // uniform per block
        const float* bias = (z == 0) ? bias0 : (z == 1) ? bias1 : bias2;
        const float scale = (z == 0) ? 0.125f : 1.0f;
        unsigned short* dst = (z == 0) ? Qb : (z == 1) ? Kb : Vb;
        #pragma unroll
        for (int fm = 0; fm < 2; fm++) {
            #pragma unroll
            for (int fn = 0; fn < 2; fn++) {
                const int coll = (n0 - z * HDIM) + wn * 64 + fn * 32 + l31;
                const float bc = bias[coll];
                const int h = coll >> 6, d = coll & 63;
                #pragma unroll
                for (int reg = 0; reg < 16; reg++) {
                    const int rowD = (reg & 3) + 8 * (reg >> 2) + 4 * lh;
                    const int m = m0 + wm * 64 + fm * 32 + rowD;
                    const int b = m >> 11, s = m & (SEQ - 1);
                    const size_t idx = (z == 2)
                        ? ((((size_t)b * NHEAD + h) * HD + d) * SEQ + s)     // V^T
                        : ((((size_t)b * NHEAD + h) * SEQ + s) * HD + d);    // Q,K
                    dst[idx] = f2bf((acc[fm][fn][reg] + bc) * scale);
                }
            }
        }
    } else {
        #pragma unroll
        for (int fm = 0; fm < 2; fm++) {
            #pragma unroll
            for (int fn = 0; fn < 2; fn++) {
                const int col = n0 + wn * 64 + fn * 32 + l31;
                const float bc = bias0[col];
                #pragma unroll
                for (int reg = 0; reg < 16; reg++) {
                    const int rowD = (reg & 3) + 8 * (reg >> 2) + 4 * lh;
                    const int m = m0 + wm * 64 + fm * 32 + rowD;
                    out[(size_t)m * HDIM + col] = acc[fm][fn][reg] + bc;
                }
            }
        }
    }
}

// ---------------------------------------------------------------------------
// MFMA banded attention (R6-proven, unchanged). One block = (bh, 64-query
// tile), 4 waves; wave wq owns queries wq*16..wq*16+15. QK^T swapped:
// S^T[key][q] = mfma(K, Q); in-register softmax (2 shfl_xor); P normalized
// pre-pack; PV = mfma(P, V^T-frags).
// ---------------------------------------------------------------------------
__global__ __launch_bounds__(256) void attn_mfma(
    const unsigned short* __restrict__ Qb, const unsigned short* __restrict__ Kb,
    const unsigned short* __restrict__ Vtg, unsigned short* __restrict__ Cb)
{
    __shared__ __align__(16) unsigned short Ks[128][72];   // [key][d]
    __shared__ __align__(16) unsigned short Qs[64][72];    // [q][d]
    __shared__ __align__(16) unsigned short Vs[64][136];   // [d][key]

    const int t = threadIdx.x;
    const int lane = t & 63;
    const int wq = t >> 6;                 // wave's query quarter (0..3)
    const int g = lane >> 4, r16 = lane & 15;
    const int q0 = blockIdx.x * 64;
    const int bh = blockIdx.y;
    const int b = bh / NHEAD, h = bh - b * NHEAD;
    const size_t base  = (size_t)bh * SEQ * HD;
    const size_t vbase = (size_t)bh * HD * SEQ;
    const int kstart = q0 - 32;
    const bool interior = (kstart >= 0) && (kstart + 127 < SEQ);

    // ---- stage K [128][64]
    {
        const int row = t >> 1, c0 = (t & 1) * 32;
        const int s = kstart + row;
        if (s >= 0 && s < SEQ) {
            const unsigned short* src = Kb + base + (size_t)s * HD + c0;
            #pragma unroll
            for (int j = 0; j < 4; j++)
                *(u16x8*)&Ks[row][c0 + 8 * j] = *(const u16x8*)(src + 8 * j);
        } else {
            const u16x8 z = {};
            #pragma unroll
            for (int j = 0; j < 4; j++)
                *(u16x8*)&Ks[row][c0 + 8 * j] = z;
        }
    }
    // ---- stage Q [64][64]
    {
        const int row = t >> 2, c0 = (t & 3) * 16;
        const unsigned short* src = Qb + base + (size_t)(q0 + row) * HD + c0;
        *(u16x8*)&Qs[row][c0] = *(const u16x8*)src;
        *(u16x8*)&Qs[row][c0 + 8] = *(const u16x8*)(src + 8);
    }
    // ---- stage V^T [64][128]
    {
        const int row = t >> 2, c0 = (t & 3) * 32;
        const unsigned short* src = Vtg + vbase + (size_t)row * SEQ + kstart + c0;
        if (interior) {
            #pragma unroll
            for (int j = 0; j < 4; j++)
                *(u16x8*)&Vs[row][c0 + 8 * j] = *(const u16x8*)(src + 8 * j);
        } else {
            for (int e = 0; e < 32; e++) {
                const int s = kstart + c0 + e;
                Vs[row][c0 + e] = (s >= 0 && s < SEQ) ? src[e] : (unsigned short)0;
            }
        }
    }
    __syncthreads();

    // ---- QK^T (swapped): sacc[mf] = S^T rows 16mf+4g+0..3, col q=r16
    s16x8 qf[2];
    {
        const unsigned short* p = &Qs[wq * 16 + r16][0];
        #pragma unroll
        for (int c = 0; c < 2; c++)
            qf[c] = mk_frag(*(const uint2*)(p + c * 32 + 4 * g),
                            *(const uint2*)(p + c * 32 + 16 + 4 * g));
    }
    f32x4 sacc[8] = {};
    #pragma unroll
    for (int mf = 0; mf < 8; mf++) {
        const unsigned short* p = &Ks[mf * 16 + r16][0];
        #pragma unroll
        for (int c = 0; c < 2; c++) {
            s16x8 kf = mk_frag(*(const uint2*)(p + c * 32 + 4 * g),
                               *(const uint2*)(p + c * 32 + 16 + 4 * g));
            MFMA(sacc[mf], kf, qf[c]);
        }
    }

    // ---- band mask + in-register softmax (query = wq*16 + r16)
    const int q_local = wq * 16 + r16;
    float mx = -1e30f;
    #pragma unroll
    for (int mf = 0; mf < 8; mf++) {
        #pragma unroll
        for (int r = 0; r < 4; r++) {
            const int key = mf * 16 + 4 * g + r;
            const int rel = key - q_local;            // j-i+32, valid [0,64]
            const int sg = kstart + key;
            const bool ok = (rel >= 0) && (rel <= 64) && (sg >= 0) && (sg < SEQ);
            const float v = ok ? sacc[mf][r] : -1e30f;
            sacc[mf][r] = v;
            mx = fmaxf(mx, v);
        }
    }
    mx = fmaxf(mx, __shfl_xor(mx, 16));
    mx = fmaxf(mx, __shfl_xor(mx, 32));
    float l = 0.f;
    #pragma unroll
    for (int mf = 0; mf < 8; mf++) {
        #pragma unroll
        for (int r = 0; r < 4; r++) {
            const float e = __expf(sacc[mf][r] - mx);
            sacc[mf][r] = e;
            l += e;
        }
    }
    l += __shfl_xor(l, 16);
    l += __shfl_xor(l, 32);
    const float inv = 1.f / l;

    // ---- pack normalized P -> bf16 A-operand frags (key chunks of 32)
    s16x8 pf[4];
    #pragma unroll
    for (int c = 0; c < 4; c++) {
        union { unsigned u[4]; s16x8 v; } pv;
        pv.u[0] = pack_bf2(sacc[2 * c][0] * inv, sacc[2 * c][1] * inv);
        pv.u[1] = pack_bf2(sacc[2 * c][2] * inv, sacc[2 * c][3] * inv);
        pv.u[2] = pack_bf2(sacc[2 * c + 1][0] * inv, sacc[2 * c + 1][1] * inv);
        pv.u[3] = pack_bf2(sacc[2 * c + 1][2] * inv, sacc[2 * c + 1][3] * inv);
        pf[c] = pv.v;
    }

    // ---- PV: ctx[q][d] = P(A) x V^T(B); cacc[nf] rows q=4g+r, col d=16nf+r16
    f32x4 cacc[4] = {};
    #pragma unroll
    for (int nf = 0; nf < 4; nf++) {
        const unsigned short* p = &Vs[nf * 16 + r16][0];
        #pragma unroll
        for (int c = 0; c < 4; c++) {
            s16x8 vf = mk_frag(*(const uint2*)(p + c * 32 + 4 * g),
                               *(const uint2*)(p + c * 32 + 16 + 4 * g));
            MFMA(cacc[nf], pf[c], vf);
        }
    }

    // ---- write ctx bf16 [b][s][h][d]
    #pragma unroll
    for (int nf = 0; nf < 4; nf++) {
        #pragma unroll
        for (int r = 0; r < 4; r++) {
            const int ql = wq * 16 + 4 * g + r;
            const int d = nf * 16 + r16;
            Cb[(((size_t)b * SEQ + q0 + ql) * NHEAD + h) * HD + d] = f2bf(cacc[nf][r]);
        }
    }
}

// ---------------------------------------------------------------------------
extern "C" void kernel_launch(void* const* d_in, const int* in_sizes, int n_in,
                              void* d_out, int out_size, void* d_ws, size_t ws_size,
                              hipStream_t stream)
{
    const float* X  = (const float*)d_in[0];
    const float* Wq = (const float*)d_in[1];
    const float* bq = (const float*)d_in[2];
    const float* Wk = (const float*)d_in[3];
    const float* bk = (const float*)d_in[4];
    const float* Wv = (const float*)d_in[5];
    const float* bv = (const float*)d_in[6];
    const float* Wo = (const float*)d_in[7];
    const float* bo = (const float*)d_in[8];
    float* out = (float*)d_out;

    // Buffer plan:
    //   ws:    [0)        Xb bf16 12.58MB  (reused as Cb after qkv gemm)
    //          [12.58M)   Vt bf16 12.58MB  ([bh][d][s] transposed)
    //          [25.17M)   Wt bf16 [2304][768] 3.54MB
    //          [28.70M)   Wot bf16 [768][768] 1.18MB
    //   d_out: [0) Qb 12.58MB, [12.58M) Kb 12.58MB -> overwritten by final out
    char* ws = (char*)d_ws;
    unsigned short* Xb  = (unsigned short*)ws;
    unsigned short* Cb  = Xb;
    unsigned short* Vt  = (unsigned short*)(ws + 12582912);
    unsigned short* Wtp = (unsigned short*)(ws + 25165824);
    unsigned short* Wot = (unsigned short*)(ws + 28704768);
    unsigned short* Qb  = (unsigned short*)d_out;
    unsigned short* Kb  = (unsigned short*)((char*)d_out + 12582912);

    x_convert<<<dim3(3072), 256, 0, stream>>>(X, Xb);
    w_transpose<<<dim3(12, 12, 4), 256, 0, stream>>>(Wq, Wk, Wv, Wo, Wtp, Wot);
    gemm_kernel<0><<<dim3(64, 18), 256, 0, stream>>>(Xb, Wtp, bq, bk, bv, Qb, Kb, Vt, nullptr);
    attn_mfma<<<dim3(32, 48), 256, 0, stream>>>(Qb, Kb, Vt, Cb);
    gemm_kernel<1><<<dim3(64, 6), 256, 0, stream>>>(Cb, Wot, bo, nullptr, nullptr,
                                                    nullptr, nullptr, nullptr, out);
}